// Round 15
// baseline (675.672 us; speedup 1.0000x reference)
//
#include <hip/hip_runtime.h>

// GCNEncoder: 2x GCNConv(64->64) + BatchNorm + ELU + global_mean_pool
// N=50000, E=800000, D=64, G=64. Inputs f32/int32, output f32.
// R13 844.7us (scatter+contended hist) -> R14 571.1us (LDS hist/pool).
// R14 profile: edge_scatter 175.8us x2 = L2 atomic wall (293G atomics/s,
// WRITE 200MB/dispatch). R15: CSR-gather aggregation (atomic-free), fused
// with BN-stats (layer 1) and out+pool (layer 2).

constexpr int GGRAPHS = 64;

__global__ void deg_kernel(const int* __restrict__ dst, int* __restrict__ deg, int E, int n) {
  int i = blockIdx.x * 256 + threadIdx.x;
  if (i < E) {
    int d = dst[i];
    if ((unsigned)d < (unsigned)n) atomicAdd(&deg[d], 1);
  }
}

// cnt[g] via per-block LDS histogram (batch sorted -> storms stay in LDS)
__global__ void cnt_kernel(const int* __restrict__ batch, int* __restrict__ cnt, int n) {
  __shared__ int h[GGRAPHS];
  int t = threadIdx.x;
  if (t < GGRAPHS) h[t] = 0;
  __syncthreads();
  for (int i = blockIdx.x * 256 + t; i < n; i += gridDim.x * 256) {
    int g = batch[i];
    if ((unsigned)g < (unsigned)GGRAPHS) atomicAdd(&h[g], 1);
  }
  __syncthreads();
  if (t < GGRAPHS && h[t] > 0) atomicAdd(&cnt[t], h[t]);
}

// 1 block, 256 threads: chunked exclusive scan of deg -> rowptr
__global__ void prefix_kernel(const int* __restrict__ deg, int* __restrict__ rowptr, int n) {
  __shared__ int part[256], base[256];
  int t = threadIdx.x;
  int chunk = (n + 255) / 256;
  int lo = t * chunk, hi = lo + chunk < n ? lo + chunk : n;
  int s = 0;
  for (int i = lo; i < hi; ++i) s += deg[i];
  part[t] = s;
  __syncthreads();
  if (t == 0) {
    int acc = 0;
    for (int k = 0; k < 256; ++k) { base[k] = acc; acc += part[k]; }
    rowptr[n] = acc;
  }
  __syncthreads();
  int acc = base[t];
  for (int i = lo; i < hi; ++i) { rowptr[i] = acc; acc += deg[i]; }
}

__global__ void fill_kernel(const int* __restrict__ srcp, const int* __restrict__ dstp,
                            const int* __restrict__ rowptr, int* __restrict__ slot,
                            int* __restrict__ col, int E, int n) {
  int e = blockIdx.x * 256 + threadIdx.x;
  if (e >= E) return;
  int s = srcp[e], d = dstp[e];
  if ((unsigned)s >= (unsigned)n || (unsigned)d >= (unsigned)n) return;
  int pos = rowptr[d] + atomicAdd(&slot[d], 1);
  col[pos] = s;
}

__global__ void dinv_kernel(const int* __restrict__ deg, float* __restrict__ dinv, int n) {
  int i = blockIdx.x * 256 + threadIdx.x;
  if (i < n) dinv[i] = rsqrtf((float)deg[i] + 1.0f);
}

// Y[n,64] = X[n,64] @ W[64,64]; block = 4 rows x 64 cols
__global__ void mm64_kernel(const float* __restrict__ X, const float* __restrict__ W,
                            float* __restrict__ Y, int n) {
  __shared__ float Ws[64][64];
  __shared__ float xs[4][64];
  int tid = threadIdx.x;
  for (int i = tid; i < 64 * 64; i += 256) Ws[i >> 6][i & 63] = W[i];
  int rr = tid >> 6, c = tid & 63;
  int row = blockIdx.x * 4 + rr;
  xs[rr][c] = (row < n) ? X[row * 64 + c] : 0.0f;
  __syncthreads();
  float acc = 0.0f;
#pragma unroll
  for (int k = 0; k < 64; ++k) acc = fmaf(xs[rr][k], Ws[k][c], acc);
  if (row < n) Y[row * 64 + c] = acc;
}

// BN affine + ELU on X rows, then @W
__global__ void bn_elu_mm64_kernel(const float* __restrict__ X, const float* __restrict__ W,
                                   const float* __restrict__ ss, float* __restrict__ Y, int n) {
  __shared__ float Ws[64][64];
  __shared__ float xs[4][64];
  int tid = threadIdx.x;
  for (int i = tid; i < 64 * 64; i += 256) Ws[i >> 6][i & 63] = W[i];
  int rr = tid >> 6, c = tid & 63;
  int row = blockIdx.x * 4 + rr;
  float v = 0.0f;
  if (row < n) {
    v = X[row * 64 + c] * ss[c] + ss[64 + c];
    v = v > 0.0f ? v : expm1f(v);
  }
  xs[rr][c] = v;
  __syncthreads();
  float acc = 0.0f;
#pragma unroll
  for (int k = 0; k < 64; ++k) acc = fmaf(xs[rr][k], Ws[k][c], acc);
  if (row < n) Y[row * 64 + c] = acc;
}

// Layer-1 aggregation (CSR gather, atomic-free) fused with self-loop, bias,
// and BN sum/sumsq. One wave per row (64 lanes = 64 ch), grid-stride.
__global__ void gather_agg_bnstats_kernel(const int* __restrict__ rowptr,
                                          const int* __restrict__ col,
                                          const float* __restrict__ dinv,
                                          const float* __restrict__ H,
                                          const float* __restrict__ b1,
                                          float* __restrict__ OUT,
                                          float* __restrict__ bns, int n) {
  int t = threadIdx.x;
  int ch = t & 63;
  int wave = t >> 6;
  float bias = b1[ch];
  float s = 0.0f, s2 = 0.0f;
  for (int row = blockIdx.x * 4 + wave; row < n; row += gridDim.x * 4) {
    int p0 = rowptr[row], p1 = rowptr[row + 1];
    float acc = 0.0f;
    for (int p = p0; p < p1; ++p) {
      int j = col[p];
      acc = fmaf(H[(size_t)j * 64 + ch], dinv[j], acc);
    }
    float di = dinv[row];
    float v = acc * di + H[(size_t)row * 64 + ch] * di * di + bias;
    OUT[(size_t)row * 64 + ch] = v;
    s += v;
    s2 += v * v;
  }
  __shared__ float ls[256], ls2[256];
  ls[t] = s;
  ls2[t] = s2;
  __syncthreads();
  if (t < 64) {
    s = ls[t] + ls[t + 64] + ls[t + 128] + ls[t + 192];
    s2 = ls2[t] + ls2[t + 64] + ls2[t + 128] + ls2[t + 192];
    atomicAdd(&bns[ch], s);
    atomicAdd(&bns[64 + ch], s2);
  }
}

__global__ void bn_final_kernel(const float* __restrict__ bns, const float* __restrict__ gamma,
                                const float* __restrict__ beta, float* __restrict__ ss, int n) {
  int ch = threadIdx.x;  // 64 threads
  float inv_n = 1.0f / (float)n;
  float mu = bns[ch] * inv_n;
  float var = bns[64 + ch] * inv_n - mu * mu;
  var = fmaxf(var, 0.0f);
  float sc = gamma[ch] * rsqrtf(var + 1e-5f);
  ss[ch] = sc;
  ss[64 + ch] = beta[ch] - mu * sc;
}

// Layer-2 aggregation (CSR gather) fused with output write and LDS mean-pool.
// Block = 64 consecutive rows (sorted batch -> <=2 graphs/block typically).
__global__ void gather_out_pool_kernel(const int* __restrict__ rowptr,
                                       const int* __restrict__ col,
                                       const float* __restrict__ dinv,
                                       const float* __restrict__ H,
                                       const float* __restrict__ b2,
                                       const int* __restrict__ batch,
                                       float* __restrict__ pool,
                                       float* __restrict__ out, int n) {
  __shared__ float a0[256], a1[256];
  int t = threadIdx.x;
  int ch = t & 63;
  int wave = t >> 6;
  int base = blockIdx.x * 64;
  int first = base < n - 1 ? base : n - 1;
  int lastrow = base + 63 < n - 1 ? base + 63 : n - 1;
  int g0 = batch[first];
  int glast = batch[lastrow];
  float bias = b2[ch];
  float s0 = 0.0f, s1 = 0.0f;
  for (int k = 0; k < 16; ++k) {
    int row = base + wave * 16 + k;
    if (row >= n) break;
    int p0 = rowptr[row], p1 = rowptr[row + 1];
    float acc = 0.0f;
    for (int p = p0; p < p1; ++p) {
      int j = col[p];
      acc = fmaf(H[(size_t)j * 64 + ch], dinv[j], acc);
    }
    float di = dinv[row];
    float v = acc * di + H[(size_t)row * 64 + ch] * di * di + bias;
    out[(size_t)row * 64 + ch] = v;
    int g = batch[row];
    if (g == g0) s0 += v;
    else if (g == glast) s1 += v;
    else if ((unsigned)g < (unsigned)GGRAPHS) atomicAdd(&pool[g * 64 + ch], v);
  }
  a0[t] = s0;
  a1[t] = s1;
  __syncthreads();
  if (t < 64) {  // t == ch
    float r0 = a0[t] + a0[t + 64] + a0[t + 128] + a0[t + 192];
    if ((unsigned)g0 < (unsigned)GGRAPHS) atomicAdd(&pool[g0 * 64 + t], r0);
    if (glast != g0) {
      float r1 = a1[t] + a1[t + 64] + a1[t + 128] + a1[t + 192];
      if ((unsigned)glast < (unsigned)GGRAPHS) atomicAdd(&pool[glast * 64 + t], r1);
    }
  }
}

__global__ void pool_final_kernel(const float* __restrict__ pool, const int* __restrict__ cnt,
                                  float* __restrict__ out) {
  int idx = blockIdx.x * 256 + threadIdx.x;  // 4096 total
  int g = idx >> 6;
  float c = (float)cnt[g];
  out[idx] = pool[idx] / fmaxf(c, 1.0f);
}

extern "C" void kernel_launch(void* const* d_in, const int* in_sizes, int n_in,
                              void* d_out, int out_size, void* d_ws, size_t ws_size,
                              hipStream_t stream) {
  const float* x = (const float*)d_in[0];
  const int* ei = (const int*)d_in[1];
  const int* batch = (const int*)d_in[2];
  const float* W1 = (const float*)d_in[3];
  const float* b1 = (const float*)d_in[4];
  const float* gamma = (const float*)d_in[5];
  const float* beta = (const float*)d_in[6];
  const float* W2 = (const float*)d_in[7];
  const float* b2 = (const float*)d_in[8];

  const int n = in_sizes[0] / 64;
  const int E = in_sizes[1] / 2;
  const int* srcp = ei;
  const int* dstp = ei + E;

  float* ws = (float*)d_ws;
  size_t nf = (size_t)n * 64;
  float* bufA = ws;                   // h1, then h2'
  float* bufB = ws + nf;              // pre-BN h
  float* dinv = ws + 2 * nf;          // n floats
  // zero region: degi, slot, bns, ss, cnti, pool (contiguous)
  int* degi = (int*)(dinv + n);       // n
  int* slot = degi + n;               // n
  float* bns = (float*)(slot + n);    // 128
  float* ss = bns + 128;              // 128
  int* cnti = (int*)(ss + 128);       // 64
  float* pool = (float*)(cnti + 64);  // 4096
  int* rowptr = (int*)(pool + 4096);  // n+1
  int* col = rowptr + n + 1;          // E

  float* out = (float*)d_out;  // FLOAT32 output

  size_t zbytes = (size_t)((char*)(pool + 4096) - (char*)degi);
  hipMemsetAsync(degi, 0, zbytes, stream);

  int blk = 256;
  int gridE = (E + blk - 1) / blk;
  int gridN = (n + blk - 1) / blk;
  int gridRows = (n + 3) / 4;
  int gridPool = (n + 63) / 64;

  deg_kernel<<<gridE, blk, 0, stream>>>(dstp, degi, E, n);
  cnt_kernel<<<128, blk, 0, stream>>>(batch, cnti, n);
  prefix_kernel<<<1, blk, 0, stream>>>(degi, rowptr, n);
  fill_kernel<<<gridE, blk, 0, stream>>>(srcp, dstp, rowptr, slot, col, E, n);
  dinv_kernel<<<gridN, blk, 0, stream>>>(degi, dinv, n);

  mm64_kernel<<<gridRows, blk, 0, stream>>>(x, W1, bufA, n);
  gather_agg_bnstats_kernel<<<512, blk, 0, stream>>>(rowptr, col, dinv, bufA, b1,
                                                     bufB, bns, n);
  bn_final_kernel<<<1, 64, 0, stream>>>(bns, gamma, beta, ss, n);
  bn_elu_mm64_kernel<<<gridRows, blk, 0, stream>>>(bufB, W2, ss, bufA, n);
  gather_out_pool_kernel<<<gridPool, blk, 0, stream>>>(rowptr, col, dinv, bufA, b2,
                                                       batch, pool, out, n);
  pool_final_kernel<<<(GGRAPHS * 64) / blk, blk, 0, stream>>>(pool, cnti, out + nf);
}

// Round 16
// 451.223 us; speedup vs baseline: 1.4974x; 1.4974x over previous
//
#include <hip/hip_runtime.h>

// GCNEncoder: 2x GCNConv(64->64) + BatchNorm + ELU + global_mean_pool
// N=50000, E=800000, D=64, G=64. Inputs f32/int32, output f32.
// R13 844.7 (atomic hist) -> R14 571.1 (LDS hist/pool; scatter=175.8us x2,
// L2 atomic wall) -> R15 675.7 REGRESSION (CSR gather at 512 blocks = 20%
// occupancy, latency-bound 216us). R16: gather at 1 wave/row (12500 blocks),
// shfl-staged neighbor lists for ILP; BN-stats and pool as separate passes.

constexpr int GGRAPHS = 64;

__global__ void deg_kernel(const int* __restrict__ dst, int* __restrict__ deg, int E, int n) {
  int i = blockIdx.x * 256 + threadIdx.x;
  if (i < E) {
    int d = dst[i];
    if ((unsigned)d < (unsigned)n) atomicAdd(&deg[d], 1);
  }
}

// cnt[g] via per-block LDS histogram (batch sorted -> storms stay in LDS)
__global__ void cnt_kernel(const int* __restrict__ batch, int* __restrict__ cnt, int n) {
  __shared__ int h[GGRAPHS];
  int t = threadIdx.x;
  if (t < GGRAPHS) h[t] = 0;
  __syncthreads();
  for (int i = blockIdx.x * 256 + t; i < n; i += gridDim.x * 256) {
    int g = batch[i];
    if ((unsigned)g < (unsigned)GGRAPHS) atomicAdd(&h[g], 1);
  }
  __syncthreads();
  if (t < GGRAPHS && h[t] > 0) atomicAdd(&cnt[t], h[t]);
}

// 1 block, 256 threads: chunked exclusive scan of deg -> rowptr
__global__ void prefix_kernel(const int* __restrict__ deg, int* __restrict__ rowptr, int n) {
  __shared__ int part[256], base[256];
  int t = threadIdx.x;
  int chunk = (n + 255) / 256;
  int lo = t * chunk, hi = lo + chunk < n ? lo + chunk : n;
  int s = 0;
  for (int i = lo; i < hi; ++i) s += deg[i];
  part[t] = s;
  __syncthreads();
  if (t == 0) {
    int acc = 0;
    for (int k = 0; k < 256; ++k) { base[k] = acc; acc += part[k]; }
    rowptr[n] = acc;
  }
  __syncthreads();
  int acc = base[t];
  for (int i = lo; i < hi; ++i) { rowptr[i] = acc; acc += deg[i]; }
}

__global__ void fill_kernel(const int* __restrict__ srcp, const int* __restrict__ dstp,
                            const int* __restrict__ rowptr, int* __restrict__ slot,
                            int* __restrict__ col, int E, int n) {
  int e = blockIdx.x * 256 + threadIdx.x;
  if (e >= E) return;
  int s = srcp[e], d = dstp[e];
  if ((unsigned)s >= (unsigned)n || (unsigned)d >= (unsigned)n) return;
  int pos = rowptr[d] + atomicAdd(&slot[d], 1);
  col[pos] = s;
}

__global__ void dinv_kernel(const int* __restrict__ deg, float* __restrict__ dinv, int n) {
  int i = blockIdx.x * 256 + threadIdx.x;
  if (i < n) dinv[i] = rsqrtf((float)deg[i] + 1.0f);
}

// Y[n,64] = X[n,64] @ W[64,64]; block = 4 rows x 64 cols
__global__ void mm64_kernel(const float* __restrict__ X, const float* __restrict__ W,
                            float* __restrict__ Y, int n) {
  __shared__ float Ws[64][64];
  __shared__ float xs[4][64];
  int tid = threadIdx.x;
  for (int i = tid; i < 64 * 64; i += 256) Ws[i >> 6][i & 63] = W[i];
  int rr = tid >> 6, c = tid & 63;
  int row = blockIdx.x * 4 + rr;
  xs[rr][c] = (row < n) ? X[row * 64 + c] : 0.0f;
  __syncthreads();
  float acc = 0.0f;
#pragma unroll
  for (int k = 0; k < 64; ++k) acc = fmaf(xs[rr][k], Ws[k][c], acc);
  if (row < n) Y[row * 64 + c] = acc;
}

// BN affine + ELU on X rows, then @W
__global__ void bn_elu_mm64_kernel(const float* __restrict__ X, const float* __restrict__ W,
                                   const float* __restrict__ ss, float* __restrict__ Y, int n) {
  __shared__ float Ws[64][64];
  __shared__ float xs[4][64];
  int tid = threadIdx.x;
  for (int i = tid; i < 64 * 64; i += 256) Ws[i >> 6][i & 63] = W[i];
  int rr = tid >> 6, c = tid & 63;
  int row = blockIdx.x * 4 + rr;
  float v = 0.0f;
  if (row < n) {
    v = X[row * 64 + c] * ss[c] + ss[64 + c];
    v = v > 0.0f ? v : expm1f(v);
  }
  xs[rr][c] = v;
  __syncthreads();
  float acc = 0.0f;
#pragma unroll
  for (int k = 0; k < 64; ++k) acc = fmaf(xs[rr][k], Ws[k][c], acc);
  if (row < n) Y[row * 64 + c] = acc;
}

// CSR gather, 1 wave per row (lane = channel). Neighbor ids+weights staged
// by one coalesced 64-wide load, shfl-broadcast -> H-row loads are
// independent (ILP), no per-neighbor pointer-chase.
__global__ void gather_kernel(const int* __restrict__ rowptr, const int* __restrict__ col,
                              const float* __restrict__ dinv, const float* __restrict__ H,
                              const float* __restrict__ b, float* __restrict__ OUT, int n) {
  int wave = threadIdx.x >> 6;
  int lane = threadIdx.x & 63;
  int row = blockIdx.x * 4 + wave;
  if (row >= n) return;
  int p0 = rowptr[row], p1 = rowptr[row + 1];
  float acc = 0.0f;
  for (int base = p0; base < p1; base += 64) {
    int myp = base + lane;
    int j = (myp < p1) ? col[myp] : 0;
    float w = (myp < p1) ? dinv[j] : 0.0f;
    int m = p1 - base < 64 ? p1 - base : 64;
#pragma unroll 4
    for (int k = 0; k < m; ++k) {
      int jj = __shfl(j, k);
      float ww = __shfl(w, k);
      acc = fmaf(H[(size_t)jj * 64 + lane], ww, acc);
    }
  }
  float di = dinv[row];
  float self = H[(size_t)row * 64 + lane];
  OUT[(size_t)row * 64 + lane] = fmaf(acc, di, fmaf(self, di * di, b[lane]));
}

// per-channel sum/sumsq over H [n,64]; 512 blocks grid-stride, LDS reduce
__global__ void bnstats_kernel(const float* __restrict__ H, float* __restrict__ bns, int n) {
  int t = threadIdx.x;
  int ch = t & 63;
  float s = 0.0f, s2 = 0.0f;
  int total = n * 64;
  for (int idx = blockIdx.x * 256 + t; idx < total; idx += 512 * 256) {
    float v = H[idx];
    s += v;
    s2 += v * v;
  }
  __shared__ float ls[256], ls2[256];
  ls[t] = s;
  ls2[t] = s2;
  __syncthreads();
  if (t < 64) {
    s = ls[t] + ls[t + 64] + ls[t + 128] + ls[t + 192];
    s2 = ls2[t] + ls2[t + 64] + ls2[t + 128] + ls2[t + 192];
    atomicAdd(&bns[ch], s);
    atomicAdd(&bns[64 + ch], s2);
  }
}

__global__ void bn_final_kernel(const float* __restrict__ bns, const float* __restrict__ gamma,
                                const float* __restrict__ beta, float* __restrict__ ss, int n) {
  int ch = threadIdx.x;  // 64 threads
  float inv_n = 1.0f / (float)n;
  float mu = bns[ch] * inv_n;
  float var = bns[64 + ch] * inv_n - mu * mu;
  var = fmaxf(var, 0.0f);
  float sc = gamma[ch] * rsqrtf(var + 1e-5f);
  ss[ch] = sc;
  ss[64 + ch] = beta[ch] - mu * sc;
}

// mean-pool from out: 64-row blocks, LDS reduce (sorted batch -> <=2 graphs/block)
__global__ void pool_kernel(const float* __restrict__ O, const int* __restrict__ batch,
                            float* __restrict__ pool, int n) {
  __shared__ float a0[256], a1[256];
  int t = threadIdx.x;
  int ch = t & 63;
  int grp = t >> 6;
  int base = blockIdx.x * 64;
  int first = base < n - 1 ? base : n - 1;
  int lastrow = base + 63 < n - 1 ? base + 63 : n - 1;
  int g0 = batch[first];
  int glast = batch[lastrow];
  float s0 = 0.0f, s1 = 0.0f;
  for (int k = 0; k < 16; ++k) {
    int row = base + grp * 16 + k;
    if (row >= n) break;
    float v = O[(size_t)row * 64 + ch];
    int g = batch[row];
    if (g == g0) s0 += v;
    else if (g == glast) s1 += v;
    else if ((unsigned)g < (unsigned)GGRAPHS) atomicAdd(&pool[g * 64 + ch], v);
  }
  a0[t] = s0;
  a1[t] = s1;
  __syncthreads();
  if (t < 64) {
    float r0 = a0[t] + a0[t + 64] + a0[t + 128] + a0[t + 192];
    if ((unsigned)g0 < (unsigned)GGRAPHS) atomicAdd(&pool[g0 * 64 + t], r0);
    if (glast != g0) {
      float r1 = a1[t] + a1[t + 64] + a1[t + 128] + a1[t + 192];
      if ((unsigned)glast < (unsigned)GGRAPHS) atomicAdd(&pool[glast * 64 + t], r1);
    }
  }
}

__global__ void pool_final_kernel(const float* __restrict__ pool, const int* __restrict__ cnt,
                                  float* __restrict__ out) {
  int idx = blockIdx.x * 256 + threadIdx.x;  // 4096 total
  int g = idx >> 6;
  float c = (float)cnt[g];
  out[idx] = pool[idx] / fmaxf(c, 1.0f);
}

extern "C" void kernel_launch(void* const* d_in, const int* in_sizes, int n_in,
                              void* d_out, int out_size, void* d_ws, size_t ws_size,
                              hipStream_t stream) {
  const float* x = (const float*)d_in[0];
  const int* ei = (const int*)d_in[1];
  const int* batch = (const int*)d_in[2];
  const float* W1 = (const float*)d_in[3];
  const float* b1 = (const float*)d_in[4];
  const float* gamma = (const float*)d_in[5];
  const float* beta = (const float*)d_in[6];
  const float* W2 = (const float*)d_in[7];
  const float* b2 = (const float*)d_in[8];

  const int n = in_sizes[0] / 64;
  const int E = in_sizes[1] / 2;
  const int* srcp = ei;
  const int* dstp = ei + E;

  float* ws = (float*)d_ws;
  size_t nf = (size_t)n * 64;
  float* bufA = ws;                   // h1, then h2'
  float* bufB = ws + nf;              // pre-BN h
  float* dinv = ws + 2 * nf;          // n floats
  int* degi = (int*)(dinv + n);       // n   (zero region starts here)
  int* slot = degi + n;               // n
  float* bns = (float*)(slot + n);    // 128
  float* ss = bns + 128;              // 128
  int* cnti = (int*)(ss + 128);       // 64
  float* pool = (float*)(cnti + 64);  // 4096 (zero region ends here)
  int* rowptr = (int*)(pool + 4096);  // n+1
  int* col = rowptr + n + 1;          // E

  float* out = (float*)d_out;  // FLOAT32 output

  size_t zbytes = (size_t)((char*)(pool + 4096) - (char*)degi);
  hipMemsetAsync(degi, 0, zbytes, stream);

  int blk = 256;
  int gridE = (E + blk - 1) / blk;
  int gridN = (n + blk - 1) / blk;
  int gridRows = (n + 3) / 4;
  int gridPool = (n + 63) / 64;

  deg_kernel<<<gridE, blk, 0, stream>>>(dstp, degi, E, n);
  cnt_kernel<<<128, blk, 0, stream>>>(batch, cnti, n);
  prefix_kernel<<<1, blk, 0, stream>>>(degi, rowptr, n);
  fill_kernel<<<gridE, blk, 0, stream>>>(srcp, dstp, rowptr, slot, col, E, n);
  dinv_kernel<<<gridN, blk, 0, stream>>>(degi, dinv, n);

  mm64_kernel<<<gridRows, blk, 0, stream>>>(x, W1, bufA, n);
  gather_kernel<<<gridRows, blk, 0, stream>>>(rowptr, col, dinv, bufA, b1, bufB, n);
  bnstats_kernel<<<512, blk, 0, stream>>>(bufB, bns, n);
  bn_final_kernel<<<1, 64, 0, stream>>>(bns, gamma, beta, ss, n);
  bn_elu_mm64_kernel<<<gridRows, blk, 0, stream>>>(bufB, W2, ss, bufA, n);
  gather_kernel<<<gridRows, blk, 0, stream>>>(rowptr, col, dinv, bufA, b2, out, n);
  pool_kernel<<<gridPool, blk, 0, stream>>>(out, batch, pool, n);
  pool_final_kernel<<<(GGRAPHS * 64) / blk, blk, 0, stream>>>(pool, cnti, out + nf);
}

// Round 17
// 366.683 us; speedup vs baseline: 1.8427x; 1.2306x over previous
//
#include <hip/hip_runtime.h>

// GCNEncoder: 2x GCNConv(64->64) + BatchNorm + ELU + global_mean_pool
// N=50000, E=800000, D=64, G=64. Inputs f32/int32, output f32.
// R13 844.7 -> R14 571.1 (kill hist contention) -> R15 675.7 (bad gather
// launch shape) -> R16 451.2 (1 wave/row gather + shfl staging).
// R16 profile: prefix_kernel 87.3us = single-block serial scan (0.04% occ).
// R17: hierarchical 3-pass parallel scan, dinv fused into pass 3.

constexpr int GGRAPHS = 64;

__global__ void deg_kernel(const int* __restrict__ dst, int* __restrict__ deg, int E, int n) {
  int i = blockIdx.x * 256 + threadIdx.x;
  if (i < E) {
    int d = dst[i];
    if ((unsigned)d < (unsigned)n) atomicAdd(&deg[d], 1);
  }
}

// cnt[g] via per-block LDS histogram (batch sorted -> storms stay in LDS)
__global__ void cnt_kernel(const int* __restrict__ batch, int* __restrict__ cnt, int n) {
  __shared__ int h[GGRAPHS];
  int t = threadIdx.x;
  if (t < GGRAPHS) h[t] = 0;
  __syncthreads();
  for (int i = blockIdx.x * 256 + t; i < n; i += gridDim.x * 256) {
    int g = batch[i];
    if ((unsigned)g < (unsigned)GGRAPHS) atomicAdd(&h[g], 1);
  }
  __syncthreads();
  if (t < GGRAPHS && h[t] > 0) atomicAdd(&cnt[t], h[t]);
}

// scan pass 1: per-256-tile exclusive scan (Hillis-Steele in LDS);
// rowptr[i] = local exclusive sum; bsum[b] = tile total.
__global__ void scan1_kernel(const int* __restrict__ deg, int* __restrict__ rowptr,
                             int* __restrict__ bsum, int n) {
  __shared__ int tmp[256];
  int t = threadIdx.x;
  int i = blockIdx.x * 256 + t;
  int v = (i < n) ? deg[i] : 0;
  tmp[t] = v;
  __syncthreads();
#pragma unroll
  for (int off = 1; off < 256; off <<= 1) {
    int a = (t >= off) ? tmp[t - off] : 0;
    __syncthreads();
    tmp[t] += a;
    __syncthreads();
  }
  if (i < n) rowptr[i] = tmp[t] - v;  // exclusive
  if (t == 255) bsum[blockIdx.x] = tmp[255];
}

// scan pass 2: 1 block, exclusive scan of bsum[nb] (nb <= 256); bsum[nb] = total.
__global__ void scan2_kernel(int* __restrict__ bsum, int nb) {
  __shared__ int tmp[256];
  int t = threadIdx.x;
  int v = (t < nb) ? bsum[t] : 0;
  tmp[t] = v;
  __syncthreads();
#pragma unroll
  for (int off = 1; off < 256; off <<= 1) {
    int a = (t >= off) ? tmp[t - off] : 0;
    __syncthreads();
    tmp[t] += a;
    __syncthreads();
  }
  if (t < nb) bsum[t] = tmp[t] - v;
  if (t == 255) bsum[nb] = tmp[255];
}

// scan pass 3: rowptr[i] += bsum[block]; fused dinv = rsqrt(deg+1); rowptr[n] = total.
__global__ void scan3_kernel(const int* __restrict__ deg, int* __restrict__ rowptr,
                             const int* __restrict__ bsum, float* __restrict__ dinv,
                             int n, int nb) {
  int i = blockIdx.x * 256 + threadIdx.x;
  if (i < n) {
    rowptr[i] += bsum[blockIdx.x];
    dinv[i] = rsqrtf((float)deg[i] + 1.0f);
  }
  if (i == 0) rowptr[n] = bsum[nb];
}

__global__ void fill_kernel(const int* __restrict__ srcp, const int* __restrict__ dstp,
                            const int* __restrict__ rowptr, int* __restrict__ slot,
                            int* __restrict__ col, int E, int n) {
  int e = blockIdx.x * 256 + threadIdx.x;
  if (e >= E) return;
  int s = srcp[e], d = dstp[e];
  if ((unsigned)s >= (unsigned)n || (unsigned)d >= (unsigned)n) return;
  int pos = rowptr[d] + atomicAdd(&slot[d], 1);
  col[pos] = s;
}

// Y[n,64] = X[n,64] @ W[64,64]; block = 4 rows x 64 cols
__global__ void mm64_kernel(const float* __restrict__ X, const float* __restrict__ W,
                            float* __restrict__ Y, int n) {
  __shared__ float Ws[64][64];
  __shared__ float xs[4][64];
  int tid = threadIdx.x;
  for (int i = tid; i < 64 * 64; i += 256) Ws[i >> 6][i & 63] = W[i];
  int rr = tid >> 6, c = tid & 63;
  int row = blockIdx.x * 4 + rr;
  xs[rr][c] = (row < n) ? X[row * 64 + c] : 0.0f;
  __syncthreads();
  float acc = 0.0f;
#pragma unroll
  for (int k = 0; k < 64; ++k) acc = fmaf(xs[rr][k], Ws[k][c], acc);
  if (row < n) Y[row * 64 + c] = acc;
}

// BN affine + ELU on X rows, then @W
__global__ void bn_elu_mm64_kernel(const float* __restrict__ X, const float* __restrict__ W,
                                   const float* __restrict__ ss, float* __restrict__ Y, int n) {
  __shared__ float Ws[64][64];
  __shared__ float xs[4][64];
  int tid = threadIdx.x;
  for (int i = tid; i < 64 * 64; i += 256) Ws[i >> 6][i & 63] = W[i];
  int rr = tid >> 6, c = tid & 63;
  int row = blockIdx.x * 4 + rr;
  float v = 0.0f;
  if (row < n) {
    v = X[row * 64 + c] * ss[c] + ss[64 + c];
    v = v > 0.0f ? v : expm1f(v);
  }
  xs[rr][c] = v;
  __syncthreads();
  float acc = 0.0f;
#pragma unroll
  for (int k = 0; k < 64; ++k) acc = fmaf(xs[rr][k], Ws[k][c], acc);
  if (row < n) Y[row * 64 + c] = acc;
}

// CSR gather, 1 wave per row (lane = channel), shfl-staged neighbor lists.
__global__ void gather_kernel(const int* __restrict__ rowptr, const int* __restrict__ col,
                              const float* __restrict__ dinv, const float* __restrict__ H,
                              const float* __restrict__ b, float* __restrict__ OUT, int n) {
  int wave = threadIdx.x >> 6;
  int lane = threadIdx.x & 63;
  int row = blockIdx.x * 4 + wave;
  if (row >= n) return;
  int p0 = rowptr[row], p1 = rowptr[row + 1];
  float acc = 0.0f;
  for (int base = p0; base < p1; base += 64) {
    int myp = base + lane;
    int j = (myp < p1) ? col[myp] : 0;
    float w = (myp < p1) ? dinv[j] : 0.0f;
    int m = p1 - base < 64 ? p1 - base : 64;
#pragma unroll 4
    for (int k = 0; k < m; ++k) {
      int jj = __shfl(j, k);
      float ww = __shfl(w, k);
      acc = fmaf(H[(size_t)jj * 64 + lane], ww, acc);
    }
  }
  float di = dinv[row];
  float self = H[(size_t)row * 64 + lane];
  OUT[(size_t)row * 64 + lane] = fmaf(acc, di, fmaf(self, di * di, b[lane]));
}

// per-channel sum/sumsq over H [n,64]; 512 blocks grid-stride, LDS reduce
__global__ void bnstats_kernel(const float* __restrict__ H, float* __restrict__ bns, int n) {
  int t = threadIdx.x;
  int ch = t & 63;
  float s = 0.0f, s2 = 0.0f;
  int total = n * 64;
  for (int idx = blockIdx.x * 256 + t; idx < total; idx += 512 * 256) {
    float v = H[idx];
    s += v;
    s2 += v * v;
  }
  __shared__ float ls[256], ls2[256];
  ls[t] = s;
  ls2[t] = s2;
  __syncthreads();
  if (t < 64) {
    s = ls[t] + ls[t + 64] + ls[t + 128] + ls[t + 192];
    s2 = ls2[t] + ls2[t + 64] + ls2[t + 128] + ls2[t + 192];
    atomicAdd(&bns[ch], s);
    atomicAdd(&bns[64 + ch], s2);
  }
}

__global__ void bn_final_kernel(const float* __restrict__ bns, const float* __restrict__ gamma,
                                const float* __restrict__ beta, float* __restrict__ ss, int n) {
  int ch = threadIdx.x;  // 64 threads
  float inv_n = 1.0f / (float)n;
  float mu = bns[ch] * inv_n;
  float var = bns[64 + ch] * inv_n - mu * mu;
  var = fmaxf(var, 0.0f);
  float sc = gamma[ch] * rsqrtf(var + 1e-5f);
  ss[ch] = sc;
  ss[64 + ch] = beta[ch] - mu * sc;
}

// mean-pool from out: 64-row blocks, LDS reduce (sorted batch -> <=2 graphs/block)
__global__ void pool_kernel(const float* __restrict__ O, const int* __restrict__ batch,
                            float* __restrict__ pool, int n) {
  __shared__ float a0[256], a1[256];
  int t = threadIdx.x;
  int ch = t & 63;
  int grp = t >> 6;
  int base = blockIdx.x * 64;
  int first = base < n - 1 ? base : n - 1;
  int lastrow = base + 63 < n - 1 ? base + 63 : n - 1;
  int g0 = batch[first];
  int glast = batch[lastrow];
  float s0 = 0.0f, s1 = 0.0f;
  for (int k = 0; k < 16; ++k) {
    int row = base + grp * 16 + k;
    if (row >= n) break;
    float v = O[(size_t)row * 64 + ch];
    int g = batch[row];
    if (g == g0) s0 += v;
    else if (g == glast) s1 += v;
    else if ((unsigned)g < (unsigned)GGRAPHS) atomicAdd(&pool[g * 64 + ch], v);
  }
  a0[t] = s0;
  a1[t] = s1;
  __syncthreads();
  if (t < 64) {
    float r0 = a0[t] + a0[t + 64] + a0[t + 128] + a0[t + 192];
    if ((unsigned)g0 < (unsigned)GGRAPHS) atomicAdd(&pool[g0 * 64 + t], r0);
    if (glast != g0) {
      float r1 = a1[t] + a1[t + 64] + a1[t + 128] + a1[t + 192];
      if ((unsigned)glast < (unsigned)GGRAPHS) atomicAdd(&pool[glast * 64 + t], r1);
    }
  }
}

__global__ void pool_final_kernel(const float* __restrict__ pool, const int* __restrict__ cnt,
                                  float* __restrict__ out) {
  int idx = blockIdx.x * 256 + threadIdx.x;  // 4096 total
  int g = idx >> 6;
  float c = (float)cnt[g];
  out[idx] = pool[idx] / fmaxf(c, 1.0f);
}

extern "C" void kernel_launch(void* const* d_in, const int* in_sizes, int n_in,
                              void* d_out, int out_size, void* d_ws, size_t ws_size,
                              hipStream_t stream) {
  const float* x = (const float*)d_in[0];
  const int* ei = (const int*)d_in[1];
  const int* batch = (const int*)d_in[2];
  const float* W1 = (const float*)d_in[3];
  const float* b1 = (const float*)d_in[4];
  const float* gamma = (const float*)d_in[5];
  const float* beta = (const float*)d_in[6];
  const float* W2 = (const float*)d_in[7];
  const float* b2 = (const float*)d_in[8];

  const int n = in_sizes[0] / 64;
  const int E = in_sizes[1] / 2;
  const int* srcp = ei;
  const int* dstp = ei + E;

  float* ws = (float*)d_ws;
  size_t nf = (size_t)n * 64;
  float* bufA = ws;                   // h1, then h2'
  float* bufB = ws + nf;              // pre-BN h
  float* dinv = ws + 2 * nf;          // n floats
  int* degi = (int*)(dinv + n);       // n   (zero region starts here)
  int* slot = degi + n;               // n
  float* bns = (float*)(slot + n);    // 128
  float* ss = bns + 128;              // 128
  int* cnti = (int*)(ss + 128);       // 64
  float* pool = (float*)(cnti + 64);  // 4096 (zero region ends here)
  int* rowptr = (int*)(pool + 4096);  // n+1
  int* col = rowptr + n + 1;          // E
  int* bsum = col + E;                // nb+1 (<=257)

  float* out = (float*)d_out;  // FLOAT32 output

  size_t zbytes = (size_t)((char*)(pool + 4096) - (char*)degi);
  hipMemsetAsync(degi, 0, zbytes, stream);

  int blk = 256;
  int gridE = (E + blk - 1) / blk;
  int nb = (n + 255) / 256;           // scan tiles (196 <= 256)
  int gridRows = (n + 3) / 4;
  int gridPool = (n + 63) / 64;

  deg_kernel<<<gridE, blk, 0, stream>>>(dstp, degi, E, n);
  cnt_kernel<<<128, blk, 0, stream>>>(batch, cnti, n);
  scan1_kernel<<<nb, blk, 0, stream>>>(degi, rowptr, bsum, n);
  scan2_kernel<<<1, blk, 0, stream>>>(bsum, nb);
  scan3_kernel<<<nb, blk, 0, stream>>>(degi, rowptr, bsum, dinv, n, nb);
  fill_kernel<<<gridE, blk, 0, stream>>>(srcp, dstp, rowptr, slot, col, E, n);

  mm64_kernel<<<gridRows, blk, 0, stream>>>(x, W1, bufA, n);
  gather_kernel<<<gridRows, blk, 0, stream>>>(rowptr, col, dinv, bufA, b1, bufB, n);
  bnstats_kernel<<<512, blk, 0, stream>>>(bufB, bns, n);
  bn_final_kernel<<<1, 64, 0, stream>>>(bns, gamma, beta, ss, n);
  bn_elu_mm64_kernel<<<gridRows, blk, 0, stream>>>(bufB, W2, ss, bufA, n);
  gather_kernel<<<gridRows, blk, 0, stream>>>(rowptr, col, dinv, bufA, b2, out, n);
  pool_kernel<<<gridPool, blk, 0, stream>>>(out, batch, pool, n);
  pool_final_kernel<<<(GGRAPHS * 64) / blk, blk, 0, stream>>>(pool, cnti, out + nf);
}